// Round 1
// 341.006 us; speedup vs baseline: 1.2832x; 1.2832x over previous
//
#include <hip/hip_runtime.h>
#include <math.h>

#define Bz 8
#define Cc 512
#define Hh 64
#define Ww 64
#define HW 4096
#define BK 64
#define AS (BK + 4)   // LDS row stride in shorts for proj kernel tiles
#define TS 68         // swizzled tile row stride (shorts) for outH/outW tiles

typedef __attribute__((ext_vector_type(8))) short short8;
typedef __attribute__((ext_vector_type(4))) short short4v;
typedef __attribute__((ext_vector_type(4))) float floatx4;

__device__ inline unsigned short f2bf(float x) {
    unsigned u = __float_as_uint(x);
    return (unsigned short)((u + 0x7FFFu + ((u >> 16) & 1u)) >> 16);   // RNE
}
__device__ inline float b2f(unsigned short h) {
    return __uint_as_float(((unsigned)h) << 16);
}
__device__ inline short8 ld8(const unsigned short* p) {   // 2x ds_read_b64
    short4v a = *(const short4v*)p;
    short4v b = *(const short4v*)(p + 4);
    short8 r;
    r[0]=a[0]; r[1]=a[1]; r[2]=a[2]; r[3]=a[3];
    r[4]=b[0]; r[5]=b[1]; r[6]=b[2]; r[7]=b[3];
    return r;
}
// swizzled ld8 from a [64][TS] bf16 tile: column-octet XOR (row&7), 16B granules
__device__ inline short8 ld8s(const unsigned short* base, int row, int koct) {
    return ld8(base + row * TS + (((koct ^ (row & 7))) << 3));
}

// ---------------------------------------------------------------------------
// Weight pre-convert: Wq,Wk -> bf16 hi+lo (split precision), Wv -> bf16 hi.
// layout (shorts): Wqh[32768] Wql[32768] Wkh[32768] Wkl[32768] Wvh[262144]
// ---------------------------------------------------------------------------
__global__ __launch_bounds__(256) void wconv_kernel(
    const float* __restrict__ Wq, const float* __restrict__ Wk,
    const float* __restrict__ Wv, unsigned short* __restrict__ wsc)
{
    const int i = blockIdx.x * 256 + threadIdx.x;
    if (i < 32768) {
        float x = Wq[i];
        unsigned short h = f2bf(x);
        wsc[i] = h;
        wsc[32768 + i] = f2bf(x - b2f(h));
    } else if (i < 65536) {
        int j = i - 32768;
        float x = Wk[j];
        unsigned short h = f2bf(x);
        wsc[65536 + j] = h;
        wsc[98304 + j] = f2bf(x - b2f(h));
    } else {
        int j = i - 65536;
        wsc[131072 + j] = f2bf(Wv[j]);
    }
}

// ---------------------------------------------------------------------------
// MFMA projection GEMM: outT[b][p][o] = bias[o] + sum_c W[o][c]*in[b][c][p]
// Two problems (sel = blockIdx.z>>3) share one launch for occupancy.
// BF16OUT: write bf16 (for pv), else f32.
// ---------------------------------------------------------------------------
template<int BN, bool SPLIT, bool BF16OUT>
__global__ __launch_bounds__(256) void proj_mfma_kernel(
    const float* __restrict__ in0, const float* __restrict__ in1,
    const unsigned short* __restrict__ Wh0, const unsigned short* __restrict__ Wh1,
    const unsigned short* __restrict__ Wl0, const unsigned short* __restrict__ Wl1,
    const float* __restrict__ bias0, const float* __restrict__ bias1,
    int COUT, float* __restrict__ out0, float* __restrict__ out1,
    unsigned short* __restrict__ out16)
{
    constexpr int NS = SPLIT ? 2 : 1;
    constexpr int NT = BN / 32;
    __shared__ unsigned short Ah[NS][128][AS];
    __shared__ unsigned short Bh[NS][BN][AS];
    const int sel = blockIdx.z >> 3;
    const int b   = blockIdx.z & 7;
    const float* __restrict__ in = sel ? in1 : in0;
    const unsigned short* __restrict__ Wh = sel ? Wh1 : Wh0;
    const unsigned short* __restrict__ Wl = sel ? Wl1 : Wl0;
    const float* __restrict__ bias = sel ? bias1 : bias0;
    float* __restrict__ outT = sel ? out1 : out0;

    const int t = threadIdx.x, lane = t & 63, wv = t >> 6;
    const int p0 = blockIdx.x * 128, o0 = blockIdx.y * BN;
    const float* __restrict__ inb = in + (size_t)b * Cc * HW + p0;

    const int wm = (wv & 1) * 64;
    const int wn = (wv >> 1) * (BN / 2);

    floatx4 acc[4][NT];
#pragma unroll
    for (int i = 0; i < 4; ++i)
#pragma unroll
        for (int j = 0; j < NT; ++j) acc[i][j] = (floatx4)0.f;

    const int ap = t & 127;
    const int aoct0 = t >> 7;

    for (int kt = 0; kt < Cc / BK; ++kt) {
        const int c0 = kt * BK;
        __syncthreads();
#pragma unroll
        for (int r = 0; r < 4; ++r) {
            const int oct = aoct0 + r * 2;
            const float* src = inb + (size_t)(c0 + oct * 8) * HW + ap;
            float x[8];
#pragma unroll
            for (int j = 0; j < 8; ++j) x[j] = src[(size_t)j * HW];
            unsigned short h[8];
#pragma unroll
            for (int j = 0; j < 8; ++j) h[j] = f2bf(x[j]);
            *(ushort4*)&Ah[0][ap][oct * 8]     = make_ushort4(h[0], h[1], h[2], h[3]);
            *(ushort4*)&Ah[0][ap][oct * 8 + 4] = make_ushort4(h[4], h[5], h[6], h[7]);
            if constexpr (SPLIT) {
                unsigned short l[8];
#pragma unroll
                for (int j = 0; j < 8; ++j) l[j] = f2bf(x[j] - b2f(h[j]));
                *(ushort4*)&Ah[1][ap][oct * 8]     = make_ushort4(l[0], l[1], l[2], l[3]);
                *(ushort4*)&Ah[1][ap][oct * 8 + 4] = make_ushort4(l[4], l[5], l[6], l[7]);
            }
        }
#pragma unroll
        for (int r = 0; r < BN * 8 / 256; ++r) {
            const int task = t + 256 * r;
            const int o = task >> 3, oct = task & 7;
            const unsigned short* src = Wh + (size_t)(o0 + o) * Cc + c0 + oct * 8;
            ushort4 w0 = *(const ushort4*)src;
            ushort4 w1 = *(const ushort4*)(src + 4);
            *(ushort4*)&Bh[0][o][oct * 8]     = w0;
            *(ushort4*)&Bh[0][o][oct * 8 + 4] = w1;
            if constexpr (SPLIT) {
                const unsigned short* srcl = Wl + (size_t)(o0 + o) * Cc + c0 + oct * 8;
                ushort4 l0 = *(const ushort4*)srcl;
                ushort4 l1 = *(const ushort4*)(srcl + 4);
                *(ushort4*)&Bh[1][o][oct * 8]     = l0;
                *(ushort4*)&Bh[1][o][oct * 8 + 4] = l1;
            }
        }
        __syncthreads();
#pragma unroll
        for (int ks = 0; ks < 2; ++ks) {
            const int col = ks * 32 + (lane >> 4) * 8;
            short8 af[4], al[4];
#pragma unroll
            for (int mt = 0; mt < 4; ++mt) {
                const int row = wm + mt * 16 + (lane & 15);
                af[mt] = ld8(&Ah[0][row][col]);
                if constexpr (SPLIT) al[mt] = ld8(&Ah[1][row][col]);
            }
            short8 bfr[NT], blr[NT];
#pragma unroll
            for (int nt = 0; nt < NT; ++nt) {
                const int row = wn + nt * 16 + (lane & 15);
                bfr[nt] = ld8(&Bh[0][row][col]);
                if constexpr (SPLIT) blr[nt] = ld8(&Bh[1][row][col]);
            }
#pragma unroll
            for (int mt = 0; mt < 4; ++mt)
#pragma unroll
                for (int nt = 0; nt < NT; ++nt) {
                    acc[mt][nt] = __builtin_amdgcn_mfma_f32_16x16x32_bf16(
                        af[mt], bfr[nt], acc[mt][nt], 0, 0, 0);
                    if constexpr (SPLIT) {
                        acc[mt][nt] = __builtin_amdgcn_mfma_f32_16x16x32_bf16(
                            al[mt], bfr[nt], acc[mt][nt], 0, 0, 0);
                        acc[mt][nt] = __builtin_amdgcn_mfma_f32_16x16x32_bf16(
                            af[mt], blr[nt], acc[mt][nt], 0, 0, 0);
                    }
                }
        }
    }
    const int oc = lane & 15, quad = lane >> 4;
#pragma unroll
    for (int nt = 0; nt < NT; ++nt) {
        const int o = o0 + wn + nt * 16 + oc;
        const float bs = bias[o];
#pragma unroll
        for (int mt = 0; mt < 4; ++mt) {
#pragma unroll
            for (int r = 0; r < 4; ++r) {
                const int p = p0 + wm + mt * 16 + quad * 4 + r;
                if constexpr (BF16OUT) {
                    out16[((size_t)b * HW + p) * COUT + o] = f2bf(acc[mt][nt][r] + bs);
                } else {
                    outT[((size_t)b * HW + p) * COUT + o] = acc[mt][nt][r] + bs;
                }
            }
        }
    }
}

// ---------------------------------------------------------------------------
// Scores (unchanged): fp32 logits into S[b][h][w][128] (eH | eW).
// ---------------------------------------------------------------------------
__global__ __launch_bounds__(256) void scores_kernel(
    const float* __restrict__ pqT, const float* __restrict__ pkT,
    float* __restrict__ S)
{
    const int x    = blockIdx.x;
    const int b    = blockIdx.y;
    const int mode = blockIdx.z;
    __shared__ float Q[64][65];
    __shared__ float K[64][65];
    for (int idx = threadIdx.x; idx < 4096; idx += 256) {
        int r = idx >> 6, c = idx & 63;
        int p = mode ? (x * Ww + r) : (r * Ww + x);
        size_t g = ((size_t)b * HW + p) * 64 + c;
        Q[r][c] = pqT[g];
        K[r][c] = pkT[g];
    }
    __syncthreads();
    const int qr = threadIdx.x >> 2;
    const int k0 = (threadIdx.x & 3) * 16;
    float acc[16];
#pragma unroll
    for (int j = 0; j < 16; ++j) acc[j] = 0.f;
#pragma unroll 4
    for (int c = 0; c < 64; ++c) {
        float qv = Q[qr][c];
#pragma unroll
        for (int j = 0; j < 16; ++j)
            acc[j] = fmaf(qv, K[k0 + j][c], acc[j]);
    }
    size_t o = mode ? (((size_t)(b * Hh + x) * Ww + qr) * 128 + 64 + k0)
                    : (((size_t)(b * Hh + qr) * Ww + x) * 128 + k0);
#pragma unroll
    for (int j = 0; j < 16; ++j) S[o + j] = acc[j];
}

// ---------------------------------------------------------------------------
// Softmax over 128 per (b,h,w); diag mask here; emits bf16 probabilities.
// ---------------------------------------------------------------------------
__global__ __launch_bounds__(256) void softmax_kernel(
    const float* __restrict__ S, unsigned short* __restrict__ Abf)
{
    const int wave = threadIdx.x >> 6;
    const int lane = threadIdx.x & 63;
    const size_t row = (size_t)blockIdx.x * 4 + wave;
    const int h = (int)((row / Ww) % Hh);
    const float* p = S + row * 128;
    float s0 = p[lane], s1 = p[lane + 64];
    if (lane == h) s0 = -INFINITY;
    float m = fmaxf(s0, s1);
#pragma unroll
    for (int off = 32; off > 0; off >>= 1) m = fmaxf(m, __shfl_xor(m, off));
    float e0 = __expf(s0 - m), e1 = __expf(s1 - m);
    float s = e0 + e1;
#pragma unroll
    for (int off = 32; off > 0; off >>= 1) s += __shfl_xor(s, off);
    float inv = 1.0f / s;
    Abf[row * 128 + lane]      = f2bf(e0 * inv);
    Abf[row * 128 + 64 + lane] = f2bf(e1 * inv);
}

// ---------------------------------------------------------------------------
// outH (MFMA): block=(w, ctg, b). TH16[b][w][h][c] = sum_k aH[h][k]*pv[k*64+w][c]
// D = mfma(aH_rows, PvT_rows): row=h, col=c.
// ---------------------------------------------------------------------------
__global__ __launch_bounds__(256) void outH_mfma_kernel(
    const unsigned short* __restrict__ Abf, const unsigned short* __restrict__ pvT16,
    unsigned short* __restrict__ TH16)
{
    const int w = blockIdx.x;
    const int ctg = blockIdx.y;
    const int b = blockIdx.z;
    const int t = threadIdx.x, lane = t & 63, wv = t >> 6;
    const int l15 = lane & 15, h4 = lane >> 4;
    __shared__ unsigned short A[64 * TS];    // aH[h][k], octet-swizzled
    __shared__ unsigned short Pt[64 * TS];   // pv^T[c][k], octet-swizzled

    {   // stage A: rows h, k = 0..63 of the Abf row
        const int rr = t >> 2, kq = t & 3;
        const unsigned short* src = Abf + ((((size_t)b * Hh + rr) * Ww + w) << 7) + kq * 16;
        ushort4 a0 = *(const ushort4*)(src);
        ushort4 a1 = *(const ushort4*)(src + 4);
        ushort4 a2 = *(const ushort4*)(src + 8);
        ushort4 a3 = *(const ushort4*)(src + 12);
        const int sw = (rr & 7) << 3;
        const int q0 = rr * TS + (((kq * 2) << 3) ^ sw);
        const int q1 = rr * TS + (((kq * 2 + 1) << 3) ^ sw);
        *(ushort4*)&A[q0] = a0; *(ushort4*)&A[q0 + 4] = a1;
        *(ushort4*)&A[q1] = a2; *(ushort4*)&A[q1 + 4] = a3;
    }
    __syncthreads();
    const int hm = (wv & 1) * 32, cn = (wv >> 1) * 32;
    short8 ah[2][2];
#pragma unroll
    for (int mt = 0; mt < 2; ++mt)
#pragma unroll
        for (int ks = 0; ks < 2; ++ks)
            ah[mt][ks] = ld8s(A, hm + mt * 16 + l15, ks * 4 + h4);

    for (int cc = 0; cc < 2; ++cc) {
        const int cbase = (ctg * 2 + cc) * 64;
        __syncthreads();
        {   // stage Pt[c][k] = pv[p=k*64+w][cbase+c] (transpose, u32-pair writes)
            const int kp = t >> 3, co = t & 7, k0 = kp * 2;
            const unsigned short* s0 = pvT16 + (((size_t)b * HW + (size_t)k0 * Ww + w) << 9) + cbase + co * 8;
            const unsigned short* s1 = s0 + ((size_t)Ww << 9);
            short8 r0 = *(const short8*)s0;
            short8 r1 = *(const short8*)s1;
            const int oct = k0 >> 3, klo = k0 & 7;
#pragma unroll
            for (int j = 0; j < 8; ++j) {
                const int c = co * 8 + j;
                unsigned vv = (unsigned)(unsigned short)r0[j] | ((unsigned)(unsigned short)r1[j] << 16);
                *(unsigned*)&Pt[c * TS + (((oct ^ (c & 7)) << 3) + klo)] = vv;
            }
        }
        __syncthreads();
        floatx4 acc[2][2];
#pragma unroll
        for (int i = 0; i < 2; ++i)
#pragma unroll
            for (int j = 0; j < 2; ++j) acc[i][j] = (floatx4)0.f;
        short8 pf[2][2];
#pragma unroll
        for (int nt = 0; nt < 2; ++nt)
#pragma unroll
            for (int ks = 0; ks < 2; ++ks)
                pf[nt][ks] = ld8s(Pt, cn + nt * 16 + l15, ks * 4 + h4);
#pragma unroll
        for (int ks = 0; ks < 2; ++ks)
#pragma unroll
            for (int mt = 0; mt < 2; ++mt)
#pragma unroll
                for (int nt = 0; nt < 2; ++nt)
                    acc[mt][nt] = __builtin_amdgcn_mfma_f32_16x16x32_bf16(
                        ah[mt][ks], pf[nt][ks], acc[mt][nt], 0, 0, 0);
        const int quad = lane >> 4, oc = lane & 15;
#pragma unroll
        for (int mt = 0; mt < 2; ++mt)
#pragma unroll
            for (int nt = 0; nt < 2; ++nt) {
                const int c = cn + nt * 16 + oc;
                unsigned short* dst = TH16 + ((((size_t)b * Ww + w) * Hh) << 9) + cbase + c;
#pragma unroll
                for (int r = 0; r < 4; ++r) {
                    const int hh = hm + mt * 16 + quad * 4 + r;
                    dst[(size_t)hh << 9] = f2bf(acc[mt][nt][r]);
                }
            }
    }
}

// ---------------------------------------------------------------------------
// outW + finalize (MFMA): block=(h, ctg, b).
// D = mfma(PvT_rows, aW_rows): row=c, col=w  -> coalesced f32 out/v access.
// out[b][c][h][w] = gamma*(D[c][w] + TH16[b][w][h][c]) + v
// ---------------------------------------------------------------------------
__global__ __launch_bounds__(256) void outW_mfma_kernel(
    const unsigned short* __restrict__ Abf, const unsigned short* __restrict__ pvT16,
    const unsigned short* __restrict__ TH16, const float* __restrict__ vin,
    const float* __restrict__ gamma_p, float* __restrict__ out)
{
    const int h = blockIdx.x;
    const int ctg = blockIdx.y;
    const int b = blockIdx.z;
    const int t = threadIdx.x, lane = t & 63, wv = t >> 6;
    const int l15 = lane & 15, h4 = lane >> 4;
    const float gamma = gamma_p[0];
    __shared__ unsigned short A[64 * TS];    // aW[w][k], octet-swizzled
    __shared__ unsigned short Pt[64 * TS];   // pv^T[c][k], octet-swizzled
    __shared__ unsigned short T2[64 * TS];   // TH[w][c] bf16, linear

    {   // stage A: rows w, k = 64..127 of the Abf row
        const int rr = t >> 2, kq = t & 3;
        const unsigned short* src = Abf + ((((size_t)b * Hh + h) * Ww + rr) << 7) + 64 + kq * 16;
        ushort4 a0 = *(const ushort4*)(src);
        ushort4 a1 = *(const ushort4*)(src + 4);
        ushort4 a2 = *(const ushort4*)(src + 8);
        ushort4 a3 = *(const ushort4*)(src + 12);
        const int sw = (rr & 7) << 3;
        const int q0 = rr * TS + (((kq * 2) << 3) ^ sw);
        const int q1 = rr * TS + (((kq * 2 + 1) << 3) ^ sw);
        *(ushort4*)&A[q0] = a0; *(ushort4*)&A[q0 + 4] = a1;
        *(ushort4*)&A[q1] = a2; *(ushort4*)&A[q1 + 4] = a3;
    }
    __syncthreads();
    const int cm = (wv & 1) * 32, wn = (wv >> 1) * 32;
    short8 aw[2][2];
#pragma unroll
    for (int nt = 0; nt < 2; ++nt)
#pragma unroll
        for (int ks = 0; ks < 2; ++ks)
            aw[nt][ks] = ld8s(A, wn + nt * 16 + l15, ks * 4 + h4);

    for (int cc = 0; cc < 2; ++cc) {
        const int cbase = (ctg * 2 + cc) * 64;
        __syncthreads();
        {   // stage Pt[c][k] = pv[p=h*64+k][cbase+c]
            const int kp = t >> 3, co = t & 7, k0 = kp * 2;
            const unsigned short* s0 = pvT16 + (((size_t)b * HW + (size_t)h * Ww + k0) << 9) + cbase + co * 8;
            const unsigned short* s1 = s0 + 512;
            short8 r0 = *(const short8*)s0;
            short8 r1 = *(const short8*)s1;
            const int oct = k0 >> 3, klo = k0 & 7;
#pragma unroll
            for (int j = 0; j < 8; ++j) {
                const int c = co * 8 + j;
                unsigned vv = (unsigned)(unsigned short)r0[j] | ((unsigned)(unsigned short)r1[j] << 16);
                *(unsigned*)&Pt[c * TS + (((oct ^ (c & 7)) << 3) + klo)] = vv;
            }
        }
        {   // stage T2[w][c] = TH16[b][w][h][cbase+c]
            const int wr = t >> 2, cq = t & 3;
            const unsigned short* src = TH16 + ((((size_t)b * Ww + wr) * Hh + h) << 9) + cbase + cq * 16;
            short8 t0 = *(const short8*)src;
            short8 t1 = *(const short8*)(src + 8);
#pragma unroll
            for (int j = 0; j < 4; ++j) {
                unsigned va = (unsigned)(unsigned short)t0[2 * j] | ((unsigned)(unsigned short)t0[2 * j + 1] << 16);
                *(unsigned*)&T2[wr * TS + cq * 16 + 2 * j] = va;
                unsigned vb = (unsigned)(unsigned short)t1[2 * j] | ((unsigned)(unsigned short)t1[2 * j + 1] << 16);
                *(unsigned*)&T2[wr * TS + cq * 16 + 8 + 2 * j] = vb;
            }
        }
        __syncthreads();
        floatx4 acc[2][2];
#pragma unroll
        for (int i = 0; i < 2; ++i)
#pragma unroll
            for (int j = 0; j < 2; ++j) acc[i][j] = (floatx4)0.f;
        short8 pf[2][2];
#pragma unroll
        for (int mt = 0; mt < 2; ++mt)
#pragma unroll
            for (int ks = 0; ks < 2; ++ks)
                pf[mt][ks] = ld8s(Pt, cm + mt * 16 + l15, ks * 4 + h4);
#pragma unroll
        for (int ks = 0; ks < 2; ++ks)
#pragma unroll
            for (int mt = 0; mt < 2; ++mt)
#pragma unroll
                for (int nt = 0; nt < 2; ++nt)
                    acc[mt][nt] = __builtin_amdgcn_mfma_f32_16x16x32_bf16(
                        pf[mt][ks], aw[nt][ks], acc[mt][nt], 0, 0, 0);
        const int quad = lane >> 4, oc = lane & 15;
#pragma unroll
        for (int mt = 0; mt < 2; ++mt)
#pragma unroll
            for (int nt = 0; nt < 2; ++nt) {
                const int wcol = wn + nt * 16 + oc;
#pragma unroll
                for (int r = 0; r < 4; ++r) {
                    const int c = cm + mt * 16 + quad * 4 + r;
                    const float t2v = b2f(T2[wcol * TS + c]);
                    const size_t oa = ((size_t)(b * Cc + cbase + c) * HW) + (size_t)h * Ww + wcol;
                    out[oa] = gamma * (acc[mt][nt][r] + t2v) + vin[oa];
                }
            }
    }
}

// ---------------------------------------------------------------------------
extern "C" void kernel_launch(void* const* d_in, const int* in_sizes, int n_in,
                              void* d_out, int out_size, void* d_ws, size_t ws_size,
                              hipStream_t stream)
{
    const float* q   = (const float*)d_in[0];
    const float* k   = (const float*)d_in[1];
    const float* v   = (const float*)d_in[2];
    const float* Wq  = (const float*)d_in[3];
    const float* bq  = (const float*)d_in[4];
    const float* Wk  = (const float*)d_in[5];
    const float* bk  = (const float*)d_in[6];
    const float* Wv  = (const float*)d_in[7];
    const float* bv  = (const float*)d_in[8];
    const float* gam = (const float*)d_in[9];
    float* out = (float*)d_out;
    float* ws  = (float*)d_ws;

    // ws layout (float units):
    //   pqT   [8][4096][64]  f32   @ 0          (2,097,152)
    //   pkT   [8][4096][64]  f32   @ 2,097,152  (2,097,152)
    //   pvT16 [8][4096][512] bf16  @ 4,194,304  (8,388,608 f32-equiv)
    //   S     [8][64][64][128] f32 @ 12,582,912 (4,194,304)
    //   Abf   [8][64][64][128] bf16@ 16,777,216 (2,097,152 f32-equiv)
    //   TH16  [8][64][64][512] bf16@ 18,874,368 (8,388,608 f32-equiv)
    // total 27,262,976 floats = 104 MiB.
    float* pqT = ws;
    float* pkT = ws + 2097152;
    unsigned short* pvT16 = (unsigned short*)(ws + 4194304);
    float* S   = ws + 12582912;
    unsigned short* Abf  = (unsigned short*)(ws + 16777216);
    unsigned short* TH16 = (unsigned short*)(ws + 18874368);

    // bf16 weights at the START of the S region: dead before scores_kernel.
    unsigned short* wsc = (unsigned short*)S;
    const unsigned short* Wqh = wsc;
    const unsigned short* Wql = wsc + 32768;
    const unsigned short* Wkh = wsc + 65536;
    const unsigned short* Wkl = wsc + 98304;
    const unsigned short* Wvh = wsc + 131072;

    wconv_kernel<<<1280, 256, 0, stream>>>(Wq, Wk, Wv, wsc);
    // q and k projections merged into one launch (z = 0..7 -> q, 8..15 -> k)
    proj_mfma_kernel<64, true, false><<<dim3(32, 1, 16), 256, 0, stream>>>(
        q, k, Wqh, Wkh, Wql, Wkl, bq, bk, 64, pqT, pkT, nullptr);
    proj_mfma_kernel<128, false, true><<<dim3(32, 4, 8), 256, 0, stream>>>(
        v, v, Wvh, Wvh, Wvh, Wvh, bv, bv, 512, nullptr, nullptr, pvT16);
    scores_kernel<<<dim3(64, 8, 2), 256, 0, stream>>>(pqT, pkT, S);
    softmax_kernel<<<8192, 256, 0, stream>>>(S, Abf);
    outH_mfma_kernel<<<dim3(64, 4, 8), 256, 0, stream>>>(Abf, pvT16, TH16);
    outW_mfma_kernel<<<dim3(64, 4, 8), 256, 0, stream>>>(Abf, pvT16, TH16, v, gam, out);
}

// Round 2
// 332.282 us; speedup vs baseline: 1.3169x; 1.0263x over previous
//
#include <hip/hip_runtime.h>
#include <math.h>

#define Bz 8
#define Cc 512
#define Hh 64
#define Ww 64
#define HW 4096
#define BK 64
#define AS (BK + 4)   // LDS row stride in shorts for proj kernel tiles (136B, 8B-aligned)
#define TS 68         // swizzled tile row stride (shorts) for outH/outW tiles

typedef __attribute__((ext_vector_type(8))) short short8;
typedef __attribute__((ext_vector_type(4))) short short4v;
typedef __attribute__((ext_vector_type(4))) float floatx4;

__device__ inline unsigned short f2bf(float x) {
    unsigned u = __float_as_uint(x);
    return (unsigned short)((u + 0x7FFFu + ((u >> 16) & 1u)) >> 16);   // RNE
}
__device__ inline float b2f(unsigned short h) {
    return __uint_as_float(((unsigned)h) << 16);
}
__device__ inline short8 ld8(const unsigned short* p) {   // 2x ds_read_b64
    short4v a = *(const short4v*)p;
    short4v b = *(const short4v*)(p + 4);
    short8 r;
    r[0]=a[0]; r[1]=a[1]; r[2]=a[2]; r[3]=a[3];
    r[4]=b[0]; r[5]=b[1]; r[6]=b[2]; r[7]=b[3];
    return r;
}
// swizzled ld8 from a [64][TS] bf16 tile: column-octet XOR (row&7), 16B granules
__device__ inline short8 ld8s(const unsigned short* base, int row, int koct) {
    return ld8(base + row * TS + (((koct ^ (row & 7))) << 3));
}

// ---------------------------------------------------------------------------
// Weight pre-convert: Wq,Wk -> bf16 hi+lo (split precision), Wv -> bf16 hi.
// layout (shorts): Wqh[32768] Wql[32768] Wkh[32768] Wkl[32768] Wvh[262144]
// ---------------------------------------------------------------------------
__global__ __launch_bounds__(256) void wconv_kernel(
    const float* __restrict__ Wq, const float* __restrict__ Wk,
    const float* __restrict__ Wv, unsigned short* __restrict__ wsc)
{
    const int i = blockIdx.x * 256 + threadIdx.x;
    if (i < 32768) {
        float x = Wq[i];
        unsigned short h = f2bf(x);
        wsc[i] = h;
        wsc[32768 + i] = f2bf(x - b2f(h));
    } else if (i < 65536) {
        int j = i - 32768;
        float x = Wk[j];
        unsigned short h = f2bf(x);
        wsc[65536 + j] = h;
        wsc[98304 + j] = f2bf(x - b2f(h));
    } else {
        int j = i - 65536;
        wsc[131072 + j] = f2bf(Wv[j]);
    }
}

// ---------------------------------------------------------------------------
// q/k projection (merged): 64x64 tile, K=512, split-precision 3-pass MFMA.
// Grid (64, 1, 16): x = p-tile, z = sel*8 + b.  4 blocks/CU (LDS 34.8 KB).
// outT[b][p][o] = bias[o] + sum_c W[o][c]*in[b][c][p]
// ---------------------------------------------------------------------------
__global__ __launch_bounds__(256, 4) void qkproj_kernel(
    const float* __restrict__ in0, const float* __restrict__ in1,
    const unsigned short* __restrict__ Wh0, const unsigned short* __restrict__ Wh1,
    const unsigned short* __restrict__ Wl0, const unsigned short* __restrict__ Wl1,
    const float* __restrict__ bias0, const float* __restrict__ bias1,
    float* __restrict__ out0, float* __restrict__ out1)
{
    __shared__ unsigned short Ah[2][64][AS];
    __shared__ unsigned short Bh[2][64][AS];
    const int sel = blockIdx.z >> 3;
    const int b   = blockIdx.z & 7;
    const float* __restrict__ in = sel ? in1 : in0;
    const unsigned short* __restrict__ Wh = sel ? Wh1 : Wh0;
    const unsigned short* __restrict__ Wl = sel ? Wl1 : Wl0;
    const float* __restrict__ bias = sel ? bias1 : bias0;
    float* __restrict__ outT = sel ? out1 : out0;

    const int t = threadIdx.x, lane = t & 63, wv = t >> 6;
    const int p0 = blockIdx.x * 64;
    const float* __restrict__ inb = in + (size_t)b * Cc * HW + p0;

    const int wm = (wv & 1) * 32;
    const int wn = (wv >> 1) * 32;

    floatx4 acc[2][2];
#pragma unroll
    for (int i = 0; i < 2; ++i)
#pragma unroll
        for (int j = 0; j < 2; ++j) acc[i][j] = (floatx4)0.f;

    const int pq4 = t & 15;        // p quad: rows pq4*4 .. +3
    const int cst = (t >> 4) * 4;  // c start (4 channels)

    for (int kt = 0; kt < Cc / BK; ++kt) {
        const int c0 = kt * BK;
        __syncthreads();
        // ---- stage A: 4x dwordx4 along p, transpose in-register, hi+lo bf16
        float4 xq[4];
#pragma unroll
        for (int j = 0; j < 4; ++j)
            xq[j] = *(const float4*)(inb + (size_t)(c0 + cst + j) * HW + (pq4 << 2));
#pragma unroll
        for (int jj = 0; jj < 4; ++jj) {
            unsigned short h[4], l[4];
#pragma unroll
            for (int j = 0; j < 4; ++j) {
                float xx = ((const float*)&xq[j])[jj];
                h[j] = f2bf(xx);
                l[j] = f2bf(xx - b2f(h[j]));
            }
            *(ushort4*)&Ah[0][(pq4 << 2) + jj][cst] = make_ushort4(h[0], h[1], h[2], h[3]);
            *(ushort4*)&Ah[1][(pq4 << 2) + jj][cst] = make_ushort4(l[0], l[1], l[2], l[3]);
        }
        // ---- stage B: bf16 weights hi+lo, contiguous rows
#pragma unroll
        for (int r = 0; r < 2; ++r) {
            const int task = t + 256 * r;
            const int o = task >> 3, oct = task & 7;
            const unsigned short* srch = Wh + (size_t)o * Cc + c0 + oct * 8;
            const unsigned short* srcl = Wl + (size_t)o * Cc + c0 + oct * 8;
            *(ushort4*)&Bh[0][o][oct * 8]     = *(const ushort4*)srch;
            *(ushort4*)&Bh[0][o][oct * 8 + 4] = *(const ushort4*)(srch + 4);
            *(ushort4*)&Bh[1][o][oct * 8]     = *(const ushort4*)srcl;
            *(ushort4*)&Bh[1][o][oct * 8 + 4] = *(const ushort4*)(srcl + 4);
        }
        __syncthreads();
        // ---- MFMA: 3-pass split (Ahi*Bhi + Alo*Bhi + Ahi*Blo)
#pragma unroll
        for (int ks = 0; ks < 2; ++ks) {
            const int col = ks * 32 + (lane >> 4) * 8;
            short8 af[2], al[2], bfr[2], blr[2];
#pragma unroll
            for (int mt = 0; mt < 2; ++mt) {
                const int row = wm + mt * 16 + (lane & 15);
                af[mt] = ld8(&Ah[0][row][col]);
                al[mt] = ld8(&Ah[1][row][col]);
            }
#pragma unroll
            for (int nt = 0; nt < 2; ++nt) {
                const int row = wn + nt * 16 + (lane & 15);
                bfr[nt] = ld8(&Bh[0][row][col]);
                blr[nt] = ld8(&Bh[1][row][col]);
            }
#pragma unroll
            for (int mt = 0; mt < 2; ++mt)
#pragma unroll
                for (int nt = 0; nt < 2; ++nt) {
                    acc[mt][nt] = __builtin_amdgcn_mfma_f32_16x16x32_bf16(
                        af[mt], bfr[nt], acc[mt][nt], 0, 0, 0);
                    acc[mt][nt] = __builtin_amdgcn_mfma_f32_16x16x32_bf16(
                        al[mt], bfr[nt], acc[mt][nt], 0, 0, 0);
                    acc[mt][nt] = __builtin_amdgcn_mfma_f32_16x16x32_bf16(
                        af[mt], blr[nt], acc[mt][nt], 0, 0, 0);
                }
        }
    }
    // ---- epilogue: D row=(lane>>4)*4+reg (p), col=lane&15 (o)
    const int oc = lane & 15, qd = lane >> 4;
#pragma unroll
    for (int nt = 0; nt < 2; ++nt) {
        const int o = wn + nt * 16 + oc;
        const float bs = bias[o];
#pragma unroll
        for (int mt = 0; mt < 2; ++mt)
#pragma unroll
            for (int r = 0; r < 4; ++r) {
                const int p = p0 + wm + mt * 16 + qd * 4 + r;
                outT[((size_t)b * HW + p) * 64 + o] = acc[mt][nt][r] + bs;
            }
    }
}

// ---------------------------------------------------------------------------
// v projection: 128x128 tile, bf16 out.  Grid (32, 4, 8), 4 blocks/CU.
// ---------------------------------------------------------------------------
__global__ __launch_bounds__(256, 4) void vproj_kernel(
    const float* __restrict__ in, const unsigned short* __restrict__ Wh,
    const float* __restrict__ bias, unsigned short* __restrict__ out16)
{
    __shared__ unsigned short Ah[128][AS];
    __shared__ unsigned short Bh[128][AS];
    const int b = blockIdx.z;
    const int t = threadIdx.x, lane = t & 63, wv = t >> 6;
    const int p0 = blockIdx.x * 128, o0 = blockIdx.y * 128;
    const float* __restrict__ inb = in + (size_t)b * Cc * HW + p0;
    const int wm = (wv & 1) * 64, wn = (wv >> 1) * 64;

    floatx4 acc[4][4];
#pragma unroll
    for (int i = 0; i < 4; ++i)
#pragma unroll
        for (int j = 0; j < 4; ++j) acc[i][j] = (floatx4)0.f;

    const int pq4 = t & 31;        // p quad: rows pq4*4 .. +3
    const int oct = t >> 5;        // c octet: c = oct*8 + j

    for (int kt = 0; kt < Cc / BK; ++kt) {
        const int c0 = kt * BK;
        __syncthreads();
        // ---- stage A in two halves (keeps VGPR under the 4-block tier)
#pragma unroll
        for (int half = 0; half < 2; ++half) {
            float4 xq[4];
#pragma unroll
            for (int j = 0; j < 4; ++j)
                xq[j] = *(const float4*)(inb + (size_t)(c0 + oct * 8 + half * 4 + j) * HW + (pq4 << 2));
#pragma unroll
            for (int jj = 0; jj < 4; ++jj) {
                unsigned short h[4];
#pragma unroll
                for (int j = 0; j < 4; ++j) h[j] = f2bf(((const float*)&xq[j])[jj]);
                *(ushort4*)&Ah[(pq4 << 2) + jj][oct * 8 + half * 4] =
                    make_ushort4(h[0], h[1], h[2], h[3]);
            }
        }
        // ---- stage B
#pragma unroll
        for (int r = 0; r < 4; ++r) {
            const int task = t + 256 * r;
            const int o = task >> 3, oc8 = task & 7;
            const unsigned short* src = Wh + (size_t)(o0 + o) * Cc + c0 + oc8 * 8;
            *(ushort4*)&Bh[o][oc8 * 8]     = *(const ushort4*)src;
            *(ushort4*)&Bh[o][oc8 * 8 + 4] = *(const ushort4*)(src + 4);
        }
        __syncthreads();
#pragma unroll
        for (int ks = 0; ks < 2; ++ks) {
            const int col = ks * 32 + (lane >> 4) * 8;
            short8 af[4], bfr[4];
#pragma unroll
            for (int mt = 0; mt < 4; ++mt)
                af[mt] = ld8(&Ah[wm + mt * 16 + (lane & 15)][col]);
#pragma unroll
            for (int nt = 0; nt < 4; ++nt)
                bfr[nt] = ld8(&Bh[wn + nt * 16 + (lane & 15)][col]);
#pragma unroll
            for (int mt = 0; mt < 4; ++mt)
#pragma unroll
                for (int nt = 0; nt < 4; ++nt)
                    acc[mt][nt] = __builtin_amdgcn_mfma_f32_16x16x32_bf16(
                        af[mt], bfr[nt], acc[mt][nt], 0, 0, 0);
        }
    }
    const int oc = lane & 15, qd = lane >> 4;
#pragma unroll
    for (int nt = 0; nt < 4; ++nt) {
        const int o = o0 + wn + nt * 16 + oc;
        const float bs = bias[o];
#pragma unroll
        for (int mt = 0; mt < 4; ++mt)
#pragma unroll
            for (int r = 0; r < 4; ++r) {
                const int p = p0 + wm + mt * 16 + qd * 4 + r;
                out16[((size_t)b * HW + p) * 512 + o] = f2bf(acc[mt][nt][r] + bs);
            }
    }
}

// ---------------------------------------------------------------------------
// Scores: K staged transposed (Kt[c][k]) -> inner loop reads 4x ds_read_b128.
// ---------------------------------------------------------------------------
__global__ __launch_bounds__(256) void scores_kernel(
    const float* __restrict__ pqT, const float* __restrict__ pkT,
    float* __restrict__ S)
{
    const int x    = blockIdx.x;
    const int b    = blockIdx.y;
    const int mode = blockIdx.z;
    __shared__ float Q[64][65];
    __shared__ float Kt[64][68];   // [c][k]
    for (int idx = threadIdx.x; idx < 4096; idx += 256) {
        int r = idx >> 6, c = idx & 63;
        int p = mode ? (x * Ww + r) : (r * Ww + x);
        size_t g = ((size_t)b * HW + p) * 64 + c;
        Q[r][c] = pqT[g];
        Kt[c][r] = pkT[g];
    }
    __syncthreads();
    const int qr = threadIdx.x >> 2;
    const int k0 = (threadIdx.x & 3) * 16;
    float acc[16];
#pragma unroll
    for (int j = 0; j < 16; ++j) acc[j] = 0.f;
#pragma unroll 2
    for (int c = 0; c < 64; ++c) {
        const float qv = Q[qr][c];
        const float4 kv0 = *(const float4*)&Kt[c][k0];
        const float4 kv1 = *(const float4*)&Kt[c][k0 + 4];
        const float4 kv2 = *(const float4*)&Kt[c][k0 + 8];
        const float4 kv3 = *(const float4*)&Kt[c][k0 + 12];
        acc[0]  = fmaf(qv, kv0.x, acc[0]);
        acc[1]  = fmaf(qv, kv0.y, acc[1]);
        acc[2]  = fmaf(qv, kv0.z, acc[2]);
        acc[3]  = fmaf(qv, kv0.w, acc[3]);
        acc[4]  = fmaf(qv, kv1.x, acc[4]);
        acc[5]  = fmaf(qv, kv1.y, acc[5]);
        acc[6]  = fmaf(qv, kv1.z, acc[6]);
        acc[7]  = fmaf(qv, kv1.w, acc[7]);
        acc[8]  = fmaf(qv, kv2.x, acc[8]);
        acc[9]  = fmaf(qv, kv2.y, acc[9]);
        acc[10] = fmaf(qv, kv2.z, acc[10]);
        acc[11] = fmaf(qv, kv2.w, acc[11]);
        acc[12] = fmaf(qv, kv3.x, acc[12]);
        acc[13] = fmaf(qv, kv3.y, acc[13]);
        acc[14] = fmaf(qv, kv3.z, acc[14]);
        acc[15] = fmaf(qv, kv3.w, acc[15]);
    }
    size_t o = mode ? (((size_t)(b * Hh + x) * Ww + qr) * 128 + 64 + k0)
                    : (((size_t)(b * Hh + qr) * Ww + x) * 128 + k0);
#pragma unroll
    for (int j = 0; j < 16; ++j) S[o + j] = acc[j];
}

// ---------------------------------------------------------------------------
// Softmax over 128 per (b,h,w); diag mask here; emits bf16 probabilities.
// ---------------------------------------------------------------------------
__global__ __launch_bounds__(256) void softmax_kernel(
    const float* __restrict__ S, unsigned short* __restrict__ Abf)
{
    const int wave = threadIdx.x >> 6;
    const int lane = threadIdx.x & 63;
    const size_t row = (size_t)blockIdx.x * 4 + wave;
    const int h = (int)((row / Ww) % Hh);
    const float* p = S + row * 128;
    float s0 = p[lane], s1 = p[lane + 64];
    if (lane == h) s0 = -INFINITY;
    float m = fmaxf(s0, s1);
#pragma unroll
    for (int off = 32; off > 0; off >>= 1) m = fmaxf(m, __shfl_xor(m, off));
    float e0 = __expf(s0 - m), e1 = __expf(s1 - m);
    float s = e0 + e1;
#pragma unroll
    for (int off = 32; off > 0; off >>= 1) s += __shfl_xor(s, off);
    float inv = 1.0f / s;
    Abf[row * 128 + lane]      = f2bf(e0 * inv);
    Abf[row * 128 + 64 + lane] = f2bf(e1 * inv);
}

// ---------------------------------------------------------------------------
// outH (MFMA): block=(w, ctg, b). TH16[b][w][h][c] = sum_k aH[h][k]*pv[k*64+w][c]
// ---------------------------------------------------------------------------
__global__ __launch_bounds__(256) void outH_mfma_kernel(
    const unsigned short* __restrict__ Abf, const unsigned short* __restrict__ pvT16,
    unsigned short* __restrict__ TH16)
{
    const int w = blockIdx.x;
    const int ctg = blockIdx.y;
    const int b = blockIdx.z;
    const int t = threadIdx.x, lane = t & 63, wv = t >> 6;
    const int l15 = lane & 15, h4 = lane >> 4;
    __shared__ unsigned short A[64 * TS];    // aH[h][k], octet-swizzled
    __shared__ unsigned short Pt[64 * TS];   // pv^T[c][k], octet-swizzled

    {
        const int rr = t >> 2, kq = t & 3;
        const unsigned short* src = Abf + ((((size_t)b * Hh + rr) * Ww + w) << 7) + kq * 16;
        ushort4 a0 = *(const ushort4*)(src);
        ushort4 a1 = *(const ushort4*)(src + 4);
        ushort4 a2 = *(const ushort4*)(src + 8);
        ushort4 a3 = *(const ushort4*)(src + 12);
        const int sw = (rr & 7) << 3;
        const int q0 = rr * TS + (((kq * 2) << 3) ^ sw);
        const int q1 = rr * TS + (((kq * 2 + 1) << 3) ^ sw);
        *(ushort4*)&A[q0] = a0; *(ushort4*)&A[q0 + 4] = a1;
        *(ushort4*)&A[q1] = a2; *(ushort4*)&A[q1 + 4] = a3;
    }
    __syncthreads();
    const int hm = (wv & 1) * 32, cn = (wv >> 1) * 32;
    short8 ah[2][2];
#pragma unroll
    for (int mt = 0; mt < 2; ++mt)
#pragma unroll
        for (int ks = 0; ks < 2; ++ks)
            ah[mt][ks] = ld8s(A, hm + mt * 16 + l15, ks * 4 + h4);

    for (int cc = 0; cc < 2; ++cc) {
        const int cbase = (ctg * 2 + cc) * 64;
        __syncthreads();
        {
            const int kp = t >> 3, co = t & 7, k0 = kp * 2;
            const unsigned short* s0 = pvT16 + (((size_t)b * HW + (size_t)k0 * Ww + w) << 9) + cbase + co * 8;
            const unsigned short* s1 = s0 + ((size_t)Ww << 9);
            short8 r0 = *(const short8*)s0;
            short8 r1 = *(const short8*)s1;
            const int oct = k0 >> 3, klo = k0 & 7;
#pragma unroll
            for (int j = 0; j < 8; ++j) {
                const int c = co * 8 + j;
                unsigned vv = (unsigned)(unsigned short)r0[j] | ((unsigned)(unsigned short)r1[j] << 16);
                *(unsigned*)&Pt[c * TS + (((oct ^ (c & 7)) << 3) + klo)] = vv;
            }
        }
        __syncthreads();
        floatx4 acc[2][2];
#pragma unroll
        for (int i = 0; i < 2; ++i)
#pragma unroll
            for (int j = 0; j < 2; ++j) acc[i][j] = (floatx4)0.f;
        short8 pf[2][2];
#pragma unroll
        for (int nt = 0; nt < 2; ++nt)
#pragma unroll
            for (int ks = 0; ks < 2; ++ks)
                pf[nt][ks] = ld8s(Pt, cn + nt * 16 + l15, ks * 4 + h4);
#pragma unroll
        for (int ks = 0; ks < 2; ++ks)
#pragma unroll
            for (int mt = 0; mt < 2; ++mt)
#pragma unroll
                for (int nt = 0; nt < 2; ++nt)
                    acc[mt][nt] = __builtin_amdgcn_mfma_f32_16x16x32_bf16(
                        ah[mt][ks], pf[nt][ks], acc[mt][nt], 0, 0, 0);
        const int quad = lane >> 4, oc = lane & 15;
#pragma unroll
        for (int mt = 0; mt < 2; ++mt)
#pragma unroll
            for (int nt = 0; nt < 2; ++nt) {
                const int c = cn + nt * 16 + oc;
                unsigned short* dst = TH16 + ((((size_t)b * Ww + w) * Hh) << 9) + cbase + c;
#pragma unroll
                for (int r = 0; r < 4; ++r) {
                    const int hh = hm + mt * 16 + quad * 4 + r;
                    dst[(size_t)hh << 9] = f2bf(acc[mt][nt][r]);
                }
            }
    }
}

// ---------------------------------------------------------------------------
// outW + finalize (MFMA): block=(h, ctg, b).
// out[b][c][h][w] = gamma*(D[c][w] + TH16[b][w][h][c]) + v
// ---------------------------------------------------------------------------
__global__ __launch_bounds__(256) void outW_mfma_kernel(
    const unsigned short* __restrict__ Abf, const unsigned short* __restrict__ pvT16,
    const unsigned short* __restrict__ TH16, const float* __restrict__ vin,
    const float* __restrict__ gamma_p, float* __restrict__ out)
{
    const int h = blockIdx.x;
    const int ctg = blockIdx.y;
    const int b = blockIdx.z;
    const int t = threadIdx.x, lane = t & 63, wv = t >> 6;
    const int l15 = lane & 15, h4 = lane >> 4;
    const float gamma = gamma_p[0];
    __shared__ unsigned short A[64 * TS];    // aW[w][k], octet-swizzled
    __shared__ unsigned short Pt[64 * TS];   // pv^T[c][k], octet-swizzled
    __shared__ unsigned short T2[64 * TS];   // TH[w][c] bf16, linear

    {
        const int rr = t >> 2, kq = t & 3;
        const unsigned short* src = Abf + ((((size_t)b * Hh + h) * Ww + rr) << 7) + 64 + kq * 16;
        ushort4 a0 = *(const ushort4*)(src);
        ushort4 a1 = *(const ushort4*)(src + 4);
        ushort4 a2 = *(const ushort4*)(src + 8);
        ushort4 a3 = *(const ushort4*)(src + 12);
        const int sw = (rr & 7) << 3;
        const int q0 = rr * TS + (((kq * 2) << 3) ^ sw);
        const int q1 = rr * TS + (((kq * 2 + 1) << 3) ^ sw);
        *(ushort4*)&A[q0] = a0; *(ushort4*)&A[q0 + 4] = a1;
        *(ushort4*)&A[q1] = a2; *(ushort4*)&A[q1 + 4] = a3;
    }
    __syncthreads();
    const int cm = (wv & 1) * 32, wn = (wv >> 1) * 32;
    short8 aw[2][2];
#pragma unroll
    for (int nt = 0; nt < 2; ++nt)
#pragma unroll
        for (int ks = 0; ks < 2; ++ks)
            aw[nt][ks] = ld8s(A, wn + nt * 16 + l15, ks * 4 + h4);

    for (int cc = 0; cc < 2; ++cc) {
        const int cbase = (ctg * 2 + cc) * 64;
        __syncthreads();
        {
            const int kp = t >> 3, co = t & 7, k0 = kp * 2;
            const unsigned short* s0 = pvT16 + (((size_t)b * HW + (size_t)h * Ww + k0) << 9) + cbase + co * 8;
            const unsigned short* s1 = s0 + 512;
            short8 r0 = *(const short8*)s0;
            short8 r1 = *(const short8*)s1;
            const int oct = k0 >> 3, klo = k0 & 7;
#pragma unroll
            for (int j = 0; j < 8; ++j) {
                const int c = co * 8 + j;
                unsigned vv = (unsigned)(unsigned short)r0[j] | ((unsigned)(unsigned short)r1[j] << 16);
                *(unsigned*)&Pt[c * TS + (((oct ^ (c & 7)) << 3) + klo)] = vv;
            }
        }
        {
            const int wr = t >> 2, cq = t & 3;
            const unsigned short* src = TH16 + ((((size_t)b * Ww + wr) * Hh + h) << 9) + cbase + cq * 16;
            short8 t0 = *(const short8*)src;
            short8 t1 = *(const short8*)(src + 8);
#pragma unroll
            for (int j = 0; j < 4; ++j) {
                unsigned va = (unsigned)(unsigned short)t0[2 * j] | ((unsigned)(unsigned short)t0[2 * j + 1] << 16);
                *(unsigned*)&T2[wr * TS + cq * 16 + 2 * j] = va;
                unsigned vb = (unsigned)(unsigned short)t1[2 * j] | ((unsigned)(unsigned short)t1[2 * j + 1] << 16);
                *(unsigned*)&T2[wr * TS + cq * 16 + 8 + 2 * j] = vb;
            }
        }
        __syncthreads();
        floatx4 acc[2][2];
#pragma unroll
        for (int i = 0; i < 2; ++i)
#pragma unroll
            for (int j = 0; j < 2; ++j) acc[i][j] = (floatx4)0.f;
        short8 pf[2][2];
#pragma unroll
        for (int mt = 0; mt < 2; ++mt)
#pragma unroll
            for (int ks = 0; ks < 2; ++ks)
                pf[mt][ks] = ld8s(Pt, cm + mt * 16 + l15, ks * 4 + h4);
#pragma unroll
        for (int ks = 0; ks < 2; ++ks)
#pragma unroll
            for (int mt = 0; mt < 2; ++mt)
#pragma unroll
                for (int nt = 0; nt < 2; ++nt)
                    acc[mt][nt] = __builtin_amdgcn_mfma_f32_16x16x32_bf16(
                        pf[mt][ks], aw[nt][ks], acc[mt][nt], 0, 0, 0);
        const int quad = lane >> 4, oc = lane & 15;
#pragma unroll
        for (int mt = 0; mt < 2; ++mt)
#pragma unroll
            for (int nt = 0; nt < 2; ++nt) {
                const int wcol = wn + nt * 16 + oc;
#pragma unroll
                for (int r = 0; r < 4; ++r) {
                    const int c = cm + mt * 16 + quad * 4 + r;
                    const float t2v = b2f(T2[wcol * TS + c]);
                    const size_t oa = ((size_t)(b * Cc + cbase + c) * HW) + (size_t)h * Ww + wcol;
                    out[oa] = gamma * (acc[mt][nt][r] + t2v) + vin[oa];
                }
            }
    }
}

// ---------------------------------------------------------------------------
extern "C" void kernel_launch(void* const* d_in, const int* in_sizes, int n_in,
                              void* d_out, int out_size, void* d_ws, size_t ws_size,
                              hipStream_t stream)
{
    const float* q   = (const float*)d_in[0];
    const float* k   = (const float*)d_in[1];
    const float* v   = (const float*)d_in[2];
    const float* Wq  = (const float*)d_in[3];
    const float* bq  = (const float*)d_in[4];
    const float* Wk  = (const float*)d_in[5];
    const float* bk  = (const float*)d_in[6];
    const float* Wv  = (const float*)d_in[7];
    const float* bv  = (const float*)d_in[8];
    const float* gam = (const float*)d_in[9];
    float* out = (float*)d_out;
    float* ws  = (float*)d_ws;

    // ws layout (float units):
    //   pqT   [8][4096][64]  f32   @ 0          (2,097,152)
    //   pkT   [8][4096][64]  f32   @ 2,097,152  (2,097,152)
    //   pvT16 [8][4096][512] bf16  @ 4,194,304  (8,388,608 f32-equiv)
    //   S     [8][64][64][128] f32 @ 12,582,912 (4,194,304)
    //   Abf   [8][64][64][128] bf16@ 16,777,216 (2,097,152 f32-equiv)
    //   TH16  [8][64][64][512] bf16@ 18,874,368 (8,388,608 f32-equiv)
    float* pqT = ws;
    float* pkT = ws + 2097152;
    unsigned short* pvT16 = (unsigned short*)(ws + 4194304);
    float* S   = ws + 12582912;
    unsigned short* Abf  = (unsigned short*)(ws + 16777216);
    unsigned short* TH16 = (unsigned short*)(ws + 18874368);

    // bf16 weights at the START of the S region: dead before scores_kernel.
    unsigned short* wsc = (unsigned short*)S;
    const unsigned short* Wqh = wsc;
    const unsigned short* Wql = wsc + 32768;
    const unsigned short* Wkh = wsc + 65536;
    const unsigned short* Wkl = wsc + 98304;
    const unsigned short* Wvh = wsc + 131072;

    wconv_kernel<<<1280, 256, 0, stream>>>(Wq, Wk, Wv, wsc);
    qkproj_kernel<<<dim3(64, 1, 16), 256, 0, stream>>>(
        q, k, Wqh, Wkh, Wql, Wkl, bq, bk, pqT, pkT);
    vproj_kernel<<<dim3(32, 4, 8), 256, 0, stream>>>(v, Wvh, bv, pvT16);
    scores_kernel<<<dim3(64, 8, 2), 256, 0, stream>>>(pqT, pkT, S);
    softmax_kernel<<<8192, 256, 0, stream>>>(S, Abf);
    outH_mfma_kernel<<<dim3(64, 4, 8), 256, 0, stream>>>(Abf, pvT16, TH16);
    outW_mfma_kernel<<<dim3(64, 4, 8), 256, 0, stream>>>(Abf, pvT16, TH16, v, gam, out);
}